// Round 1
// baseline (172.153 us; speedup 1.0000x reference)
//
#include <hip/hip_runtime.h>
#include <hip/hip_bf16.h>
#include <math.h>

// LinearAttention: X[b,h,n,e] = Qf[b,h,n,:] . (sum_m Kf[b,h,m,:] outer Vm[b,h,m,:])[:,e]
// Qf = (elu(Q)+1)*scale ; Kf = (elu(K)+1)*mask*scale ; Vm = V*mask ; scale = N^-0.25
// Shapes: B=2, H=12, N=4096, D=64, fp32 everywhere.

#define BH_TOT 24
#define NROWS 4096
#define DD 64

__device__ __forceinline__ float elu1(float x) {
    // elu(x)+1 = x+1 (x>0) else exp(x)
    return x > 0.0f ? x + 1.0f : __expf(x);
}

// ---------------- Pass 1: partial KtV per (head, chunk) ----------------
// grid = (BH_TOT, nchunk), block = 256
// partial[(bh*nchunk + chunk)][d][e] = sum over chunk rows of Kf[n][d]*Vm[n][e]
__global__ __launch_bounds__(256) void la_pass1(
        const float* __restrict__ K, const float* __restrict__ V,
        const float* __restrict__ mask, float* __restrict__ partial,
        int nchunk, float scale) {
    const int bh    = blockIdx.x;
    const int chunk = blockIdx.y;
    const int b     = bh / 12;
    const int rowsPerChunk = NROWS / nchunk;   // multiple of 32
    const int n0 = chunk * rowsPerChunk;

    __shared__ float Ks[32][DD];
    __shared__ float Vs[32][DD];

    const int t  = threadIdx.x;
    const int e  = t & 63;        // column this thread owns
    const int g  = t >> 6;        // wave id 0..3
    const int d0 = g * 16;        // rows d0..d0+15 of KtV owned by this wave

    float acc[16];
#pragma unroll
    for (int i = 0; i < 16; ++i) acc[i] = 0.0f;

    const float* Kbase = K + (size_t)bh * NROWS * DD;
    const float* Vbase = V + (size_t)bh * NROWS * DD;

    for (int n = n0; n < n0 + rowsPerChunk; n += 32) {
        // stage 32 rows of K (transformed) and V (masked): 512 float4 loads
#pragma unroll
        for (int i = 0; i < 2; ++i) {
            int idx4 = t + i * 256;       // 0..511
            int r = idx4 >> 4;            // row within tile (0..31)
            int c = idx4 & 15;            // float4 column (0..15)
            float m = mask[(size_t)b * NROWS + n + r];
            float4 kv = ((const float4*)(Kbase + (size_t)(n + r) * DD))[c];
            float ks = m * scale;
            kv.x = elu1(kv.x) * ks;  kv.y = elu1(kv.y) * ks;
            kv.z = elu1(kv.z) * ks;  kv.w = elu1(kv.w) * ks;
            ((float4*)&Ks[r][0])[c] = kv;
            float4 vv = ((const float4*)(Vbase + (size_t)(n + r) * DD))[c];
            vv.x *= m; vv.y *= m; vv.z *= m; vv.w *= m;
            ((float4*)&Vs[r][0])[c] = vv;
        }
        __syncthreads();
#pragma unroll 4
        for (int r = 0; r < 32; ++r) {
            float v = Vs[r][e];           // lane-consecutive: 2-way (free)
#pragma unroll
            for (int i = 0; i < 16; ++i)
                acc[i] += Ks[r][d0 + i] * v;   // wave-broadcast (free)
        }
        __syncthreads();
    }

    float* out = partial + ((size_t)bh * nchunk + chunk) * (DD * DD);
#pragma unroll
    for (int i = 0; i < 16; ++i)
        out[(d0 + i) * DD + e] = acc[i];
}

// ---------------- Pass 2: reduce partials -> KtV ----------------
// grid = BH_TOT, block = 256
__global__ __launch_bounds__(256) void la_pass2(
        const float* __restrict__ partial, float* __restrict__ ktv, int nchunk) {
    const int bh = blockIdx.x;
    const int t  = threadIdx.x;
    for (int i = t; i < DD * DD; i += 256) {
        float s = 0.0f;
        for (int c = 0; c < nchunk; ++c)
            s += partial[((size_t)bh * nchunk + c) * (DD * DD) + i];
        ktv[(size_t)bh * (DD * DD) + i] = s;
    }
}

// ---------------- Pass 3: X = Qf @ KtV ----------------
// grid = (BH_TOT, N/64), block = 256
__global__ __launch_bounds__(256) void la_pass3(
        const float* __restrict__ Q, const float* __restrict__ ktv,
        float* __restrict__ X, float scale) {
    const int bh = blockIdx.x;
    const int n0 = blockIdx.y * 64;

    __shared__ float Ms[DD][DD];   // KtV for this head, 16 KB
    __shared__ float Qs[64][DD];   // 64 transformed Q rows, 16 KB

    const int t = threadIdx.x;
    const float4* ktv4 = (const float4*)(ktv + (size_t)bh * DD * DD);
#pragma unroll
    for (int i = t; i < (DD * DD) / 4; i += 256)
        ((float4*)&Ms[0][0])[i] = ktv4[i];

    const float* Qbase = Q + (size_t)bh * NROWS * DD + (size_t)n0 * DD;
#pragma unroll
    for (int i = t; i < (64 * DD) / 4; i += 256) {
        float4 q = ((const float4*)Qbase)[i];
        q.x = elu1(q.x) * scale;  q.y = elu1(q.y) * scale;
        q.z = elu1(q.z) * scale;  q.w = elu1(q.w) * scale;
        ((float4*)&Qs[0][0])[i] = q;
    }
    __syncthreads();

    const int e  = t & 63;    // output column
    const int g  = t >> 6;    // wave id
    const int r0 = g * 16;    // rows r0..r0+15 owned by this wave

    float acc[16];
#pragma unroll
    for (int i = 0; i < 16; ++i) acc[i] = 0.0f;

#pragma unroll 8
    for (int d = 0; d < DD; ++d) {
        float m = Ms[d][e];               // lane-consecutive: 2-way (free)
#pragma unroll
        for (int i = 0; i < 16; ++i)
            acc[i] += Qs[r0 + i][d] * m;  // wave-broadcast (free)
    }

    float* out = X + (size_t)bh * NROWS * DD + (size_t)n0 * DD;
#pragma unroll
    for (int i = 0; i < 16; ++i)
        out[(r0 + i) * DD + e] = acc[i];
}

extern "C" void kernel_launch(void* const* d_in, const int* in_sizes, int n_in,
                              void* d_out, int out_size, void* d_ws, size_t ws_size,
                              hipStream_t stream) {
    const float* Q    = (const float*)d_in[0];
    const float* K    = (const float*)d_in[1];
    const float* V    = (const float*)d_in[2];
    const float* mask = (const float*)d_in[3];
    float* X = (float*)d_out;

    const float scale = (float)(1.0 / sqrt(sqrt((double)NROWS)));  // 0.125

    // workspace layout: [ktv: 24*4096 floats][partial: 24*nchunk*4096 floats]
    const size_t ktv_bytes = (size_t)BH_TOT * DD * DD * sizeof(float);
    int nchunk = 32;
    while (nchunk > 1 &&
           ktv_bytes + (size_t)BH_TOT * nchunk * DD * DD * sizeof(float) > ws_size)
        nchunk >>= 1;

    float* ktv     = (float*)d_ws;
    float* partial = ktv + (size_t)BH_TOT * DD * DD;

    la_pass1<<<dim3(BH_TOT, nchunk), 256, 0, stream>>>(K, V, mask, partial, nchunk, scale);
    la_pass2<<<BH_TOT, 256, 0, stream>>>(partial, ktv, nchunk);
    la_pass3<<<dim3(BH_TOT, NROWS / 64), 256, 0, stream>>>(Q, ktv, X, scale);
}

// Round 2
// 56.131 us; speedup vs baseline: 3.0670x; 3.0670x over previous
//
#include <hip/hip_runtime.h>
#include <hip/hip_bf16.h>
#include <math.h>

// LinearAttention: X[b,h,n,e] = Qf[b,h,n,:] . (sum_m Kf[b,h,m,:] outer Vm[b,h,m,:])[:,e]
// Qf = (elu(Q)+1)*scale ; Kf = (elu(K)+1)*mask*scale ; Vm = V*mask ; scale = N^-0.25
// Shapes: B=2, H=12, N=4096, D=64, fp32 everywhere.

#define BH_TOT 24
#define NROWS 4096
#define DD 64

__device__ __forceinline__ float elu1(float x) {
    // elu(x)+1 = x+1 (x>0) else exp(x)
    return x > 0.0f ? x + 1.0f : __expf(x);
}

// ---------------- Pass 1: partial KtV per (head, chunk) ----------------
// grid = (BH_TOT, nchunk), block = 256
// partial[(bh*nchunk + chunk)][d][e] = sum over chunk rows of Kf[n][d]*Vm[n][e]
__global__ __launch_bounds__(256) void la_pass1(
        const float* __restrict__ K, const float* __restrict__ V,
        const float* __restrict__ mask, float* __restrict__ partial,
        int nchunk, float scale) {
    const int bh    = blockIdx.x;
    const int chunk = blockIdx.y;
    const int b     = bh / 12;
    const int rowsPerChunk = NROWS / nchunk;   // multiple of 32
    const int n0 = chunk * rowsPerChunk;

    __shared__ float Ks[32][DD];
    __shared__ float Vs[32][DD];

    const int t  = threadIdx.x;
    const int e  = t & 63;        // column this thread owns
    const int g  = t >> 6;        // wave id 0..3
    const int d0 = g * 16;        // rows d0..d0+15 of KtV owned by this wave

    float acc[16];
#pragma unroll
    for (int i = 0; i < 16; ++i) acc[i] = 0.0f;

    const float* Kbase = K + (size_t)bh * NROWS * DD;
    const float* Vbase = V + (size_t)bh * NROWS * DD;

    for (int n = n0; n < n0 + rowsPerChunk; n += 32) {
        // stage 32 rows of K (transformed) and V (masked): 512 float4 loads
#pragma unroll
        for (int i = 0; i < 2; ++i) {
            int idx4 = t + i * 256;       // 0..511
            int r = idx4 >> 4;            // row within tile (0..31)
            int c = idx4 & 15;            // float4 column (0..15)
            float m = mask[(size_t)b * NROWS + n + r];
            float4 kv = ((const float4*)(Kbase + (size_t)(n + r) * DD))[c];
            float ks = m * scale;
            kv.x = elu1(kv.x) * ks;  kv.y = elu1(kv.y) * ks;
            kv.z = elu1(kv.z) * ks;  kv.w = elu1(kv.w) * ks;
            ((float4*)&Ks[r][0])[c] = kv;
            float4 vv = ((const float4*)(Vbase + (size_t)(n + r) * DD))[c];
            vv.x *= m; vv.y *= m; vv.z *= m; vv.w *= m;
            ((float4*)&Vs[r][0])[c] = vv;
        }
        __syncthreads();
#pragma unroll 4
        for (int r = 0; r < 32; ++r) {
            float v = Vs[r][e];           // lane-consecutive: 2-way (free)
#pragma unroll
            for (int i = 0; i < 16; ++i)
                acc[i] += Ks[r][d0 + i] * v;   // wave-broadcast (free)
        }
        __syncthreads();
    }

    float* out = partial + ((size_t)bh * nchunk + chunk) * (DD * DD);
#pragma unroll
    for (int i = 0; i < 16; ++i)
        out[(d0 + i) * DD + e] = acc[i];
}

// ---------------- Pass 2: reduce partials -> KtV ----------------
// grid = (BH_TOT, 4), block = 256; one float4 per thread, nchunk strided loads
__global__ __launch_bounds__(256) void la_pass2(
        const float* __restrict__ partial, float* __restrict__ ktv, int nchunk) {
    const int bh = blockIdx.x;
    const int i4 = blockIdx.y * 256 + threadIdx.x;        // 0..1023 (float4 idx in 64x64)
    const float4* base = (const float4*)partial + (size_t)bh * nchunk * (DD * DD / 4) + i4;
    float4 s = make_float4(0.f, 0.f, 0.f, 0.f);
#pragma unroll 8
    for (int c = 0; c < nchunk; ++c) {
        float4 p = base[(size_t)c * (DD * DD / 4)];
        s.x += p.x; s.y += p.y; s.z += p.z; s.w += p.w;
    }
    ((float4*)(ktv + (size_t)bh * DD * DD))[i4] = s;
}

// ---------------- Pass 3: X = Qf @ KtV ----------------
// grid = (BH_TOT, N/64), block = 256
__global__ __launch_bounds__(256) void la_pass3(
        const float* __restrict__ Q, const float* __restrict__ ktv,
        float* __restrict__ X, float scale) {
    const int bh = blockIdx.x;
    const int n0 = blockIdx.y * 64;

    __shared__ float Ms[DD][DD];   // KtV for this head, 16 KB
    __shared__ float Qs[64][DD];   // 64 transformed Q rows, 16 KB

    const int t = threadIdx.x;
    const float4* ktv4 = (const float4*)(ktv + (size_t)bh * DD * DD);
#pragma unroll
    for (int i = t; i < (DD * DD) / 4; i += 256)
        ((float4*)&Ms[0][0])[i] = ktv4[i];

    const float* Qbase = Q + (size_t)bh * NROWS * DD + (size_t)n0 * DD;
#pragma unroll
    for (int i = t; i < (64 * DD) / 4; i += 256) {
        float4 q = ((const float4*)Qbase)[i];
        q.x = elu1(q.x) * scale;  q.y = elu1(q.y) * scale;
        q.z = elu1(q.z) * scale;  q.w = elu1(q.w) * scale;
        ((float4*)&Qs[0][0])[i] = q;
    }
    __syncthreads();

    const int e  = t & 63;    // output column
    const int g  = t >> 6;    // wave id
    const int r0 = g * 16;    // rows r0..r0+15 owned by this wave

    float acc[16];
#pragma unroll
    for (int i = 0; i < 16; ++i) acc[i] = 0.0f;

#pragma unroll 8
    for (int d = 0; d < DD; ++d) {
        float m = Ms[d][e];               // lane-consecutive: 2-way (free)
#pragma unroll
        for (int i = 0; i < 16; ++i)
            acc[i] += Qs[r0 + i][d] * m;  // wave-broadcast (free)
    }

    float* out = X + (size_t)bh * NROWS * DD + (size_t)n0 * DD;
#pragma unroll
    for (int i = 0; i < 16; ++i)
        out[(r0 + i) * DD + e] = acc[i];
}

extern "C" void kernel_launch(void* const* d_in, const int* in_sizes, int n_in,
                              void* d_out, int out_size, void* d_ws, size_t ws_size,
                              hipStream_t stream) {
    const float* Q    = (const float*)d_in[0];
    const float* K    = (const float*)d_in[1];
    const float* V    = (const float*)d_in[2];
    const float* mask = (const float*)d_in[3];
    float* X = (float*)d_out;

    const float scale = (float)(1.0 / sqrt(sqrt((double)NROWS)));  // 0.125

    // workspace layout: [ktv: 24*4096 floats][partial: 24*nchunk*4096 floats]
    const size_t ktv_bytes = (size_t)BH_TOT * DD * DD * sizeof(float);
    int nchunk = 32;
    while (nchunk > 1 &&
           ktv_bytes + (size_t)BH_TOT * nchunk * DD * DD * sizeof(float) > ws_size)
        nchunk >>= 1;

    float* ktv     = (float*)d_ws;
    float* partial = ktv + (size_t)BH_TOT * DD * DD;

    la_pass1<<<dim3(BH_TOT, nchunk), 256, 0, stream>>>(K, V, mask, partial, nchunk, scale);
    la_pass2<<<dim3(BH_TOT, 4), 256, 0, stream>>>(partial, ktv, nchunk);
    la_pass3<<<dim3(BH_TOT, NROWS / 64), 256, 0, stream>>>(Q, ktv, X, scale);
}

// Round 3
// 54.783 us; speedup vs baseline: 3.1425x; 1.0246x over previous
//
#include <hip/hip_runtime.h>
#include <hip/hip_bf16.h>
#include <math.h>

// LinearAttention: X = Qf @ (Kf^T @ Vm), per (b,h).
// Qf = (elu(Q)+1)*scale ; Kf = (elu(K)+1)*m*scale ; Vm = V*m ; scale = N^-0.25
// B=2, H=12, N=4096, D=64, fp32.
//
// Strategy: SGPR-broadcast GEMV structure — the wave-uniform operand (V row in
// pass1, KtV row in pass3) is loaded via scalar loads (s_load_dwordx16) and fed
// to v_fmac as the SGPR operand; zero LDS traffic in the inner loops.

#define BH_TOT 24
#define NROWS 4096
#define DD 64
#define NCHUNK 32

__device__ __forceinline__ float elu1(float x) {
    return x > 0.0f ? x + 1.0f : __expf(x);
}

// ---------------- Pass 1: per-(head,chunk) partial KtV ----------------
// grid (24, 32), block 256. Wave w handles rows n0+w*32 .. +31.
// Lane l owns KtV row d=l; acc[e] over e=0..63.
__global__ __launch_bounds__(256) void la_pass1(
        const float* __restrict__ K, const float* __restrict__ V,
        const float* __restrict__ mask, float* __restrict__ partial,
        float scale) {
    const int bh    = blockIdx.x;
    const int chunk = blockIdx.y;
    const int b     = bh / 12;
    const int wave  = __builtin_amdgcn_readfirstlane(threadIdx.x >> 6);
    const int lane  = threadIdx.x & 63;

    const float* __restrict__ Kp = K + (size_t)bh * NROWS * DD;
    const float* __restrict__ Vp = V + (size_t)bh * NROWS * DD;
    const float* __restrict__ mp = mask + (size_t)b * NROWS;

    const int n0 = chunk * 128 + wave * 32;

    float acc[DD];
#pragma unroll
    for (int e = 0; e < DD; ++e) acc[e] = 0.0f;

#pragma unroll 1
    for (int i = 0; i < 32; ++i) {
        const int n = n0 + i;                         // wave-uniform
        const float m  = mp[n];                       // uniform -> s_load
        const float kraw = Kp[(size_t)n * DD + lane]; // coalesced VGPR load
        const float kf = elu1(kraw) * (m * m * scale);
        const float* __restrict__ Vr = Vp + (size_t)n * DD;  // uniform base
#pragma unroll
        for (int e = 0; e < DD; ++e)
            acc[e] = fmaf(kf, Vr[e], acc[e]);         // Vr[e] -> SGPR operand
    }

    // Cross-wave reduce via transposed LDS (lane-consecutive => conflict-free).
    __shared__ float red[2][DD][DD + 1];   // 33.3 KB
    if (wave >= 2) {
#pragma unroll
        for (int e = 0; e < DD; ++e) red[wave - 2][e][lane] = acc[e];
    }
    __syncthreads();
    if (wave < 2) {
#pragma unroll
        for (int e = 0; e < DD; ++e) acc[e] += red[wave][e][lane];
    }
    __syncthreads();
    if (wave == 1) {
#pragma unroll
        for (int e = 0; e < DD; ++e) red[0][e][lane] = acc[e];
    }
    __syncthreads();
    if (wave == 0) {
#pragma unroll
        for (int e = 0; e < DD; ++e) acc[e] += red[0][e][lane];
        // lane l holds KtV row l -> contiguous 256 B per lane
        float4* out = (float4*)(partial + ((size_t)bh * NCHUNK + chunk) * (DD * DD)
                                + (size_t)lane * DD);
#pragma unroll
        for (int e4 = 0; e4 < DD / 4; ++e4)
            out[e4] = make_float4(acc[e4 * 4], acc[e4 * 4 + 1],
                                  acc[e4 * 4 + 2], acc[e4 * 4 + 3]);
    }
}

// ---------------- Pass 2: reduce partials -> KtV ----------------
// grid (24, 4), block 256; one float4 per thread.
__global__ __launch_bounds__(256) void la_pass2(
        const float* __restrict__ partial, float* __restrict__ ktv) {
    const int bh = blockIdx.x;
    const int i4 = blockIdx.y * 256 + threadIdx.x;    // 0..1023
    const float4* base = (const float4*)partial + (size_t)bh * NCHUNK * (DD * DD / 4) + i4;
    float4 s = make_float4(0.f, 0.f, 0.f, 0.f);
#pragma unroll 8
    for (int c = 0; c < NCHUNK; ++c) {
        float4 p = base[(size_t)c * (DD * DD / 4)];
        s.x += p.x; s.y += p.y; s.z += p.z; s.w += p.w;
    }
    ((float4*)(ktv + (size_t)bh * DD * DD))[i4] = s;
}

// ---------------- Pass 3: X = Qf @ KtV ----------------
// grid (24, 32), block 256, 128 rows/block.
// Wave w: row-half h=w>>1 (64 rows, lane=row), col-half c=w&1 (32 cols in acc).
__global__ __launch_bounds__(256) void la_pass3(
        const float* __restrict__ Q, const float* __restrict__ ktv,
        float* __restrict__ X, float scale) {
    const int bh = blockIdx.x;
    const int n0 = blockIdx.y * 128;
    const int t    = threadIdx.x;
    const int wave = __builtin_amdgcn_readfirstlane(t >> 6);
    const int lane = t & 63;
    const int h = wave >> 1;
    const int c = wave & 1;

    __shared__ float Qs[128][DD + 1];   // 33.3 KB, pad => conflict-free column reads

    const float* __restrict__ Qbase = Q + (size_t)bh * NROWS * DD + (size_t)n0 * DD;
#pragma unroll
    for (int k = 0; k < 8; ++k) {
        int idx = t + k * 256;          // float4 index, 0..2047
        int r  = idx >> 4;
        int c4 = idx & 15;
        float4 q = ((const float4*)Qbase)[idx];
        q.x = elu1(q.x) * scale;  q.y = elu1(q.y) * scale;
        q.z = elu1(q.z) * scale;  q.w = elu1(q.w) * scale;
        Qs[r][c4 * 4 + 0] = q.x;  Qs[r][c4 * 4 + 1] = q.y;
        Qs[r][c4 * 4 + 2] = q.z;  Qs[r][c4 * 4 + 3] = q.w;
    }
    __syncthreads();

    const float* __restrict__ M = ktv + (size_t)bh * DD * DD + c * 32;  // uniform

    float acc[32];
#pragma unroll
    for (int e = 0; e < 32; ++e) acc[e] = 0.0f;

#pragma unroll 2
    for (int d = 0; d < DD; ++d) {
        const float q = Qs[h * 64 + lane][d];          // conflict-free b32
#pragma unroll
        for (int e = 0; e < 32; ++e)
            acc[e] = fmaf(q, M[(size_t)d * DD + e], acc[e]);  // SGPR operand
    }

    float4* out = (float4*)(X + (size_t)bh * NROWS * DD
                            + (size_t)(n0 + h * 64 + lane) * DD + c * 32);
#pragma unroll
    for (int e4 = 0; e4 < 8; ++e4)
        out[e4] = make_float4(acc[e4 * 4], acc[e4 * 4 + 1],
                              acc[e4 * 4 + 2], acc[e4 * 4 + 3]);
}

extern "C" void kernel_launch(void* const* d_in, const int* in_sizes, int n_in,
                              void* d_out, int out_size, void* d_ws, size_t ws_size,
                              hipStream_t stream) {
    const float* Q    = (const float*)d_in[0];
    const float* K    = (const float*)d_in[1];
    const float* V    = (const float*)d_in[2];
    const float* mask = (const float*)d_in[3];
    float* X = (float*)d_out;

    const float scale = (float)(1.0 / sqrt(sqrt((double)NROWS)));  // 0.125

    // ws: [ktv: 24*4096 floats][partial: 24*32*4096 floats] = ~13 MB
    float* ktv     = (float*)d_ws;
    float* partial = ktv + (size_t)BH_TOT * DD * DD;

    la_pass1<<<dim3(BH_TOT, NCHUNK), 256, 0, stream>>>(K, V, mask, partial, scale);
    la_pass2<<<dim3(BH_TOT, 4), 256, 0, stream>>>(partial, ktv);
    la_pass3<<<dim3(BH_TOT, NCHUNK), 256, 0, stream>>>(Q, ktv, X, scale);
}

// Round 4
// 36.992 us; speedup vs baseline: 4.6538x; 1.4809x over previous
//
#include <hip/hip_runtime.h>
#include <hip/hip_bf16.h>
#include <math.h>

// LinearAttention: X = Qf @ (Kf^T @ Vm) per (b,h); B=2 H=12 N=4096 D=64 fp32.
// Qf=(elu(Q)+1)*s ; Kf=(elu(K)+1)*m*s ; Vm=V*m ; s = N^-0.25 = 0.125 exact.
//
// MFMA formulation (bf16 in, fp32 accum):
//  pass1: per-wave 64-row slab -> partial KtV[64][64] f32 (A=Kf^T, B=Vm frags
//         gathered directly from global with imm-offset dword loads; no LDS)
//  pass2: reduce NW partials/head -> bf16 ktvT[e][d] (B-frag-friendly layout)
//  pass3: X = Qf @ KtV ; A-frags = 2x float4 per lane from Q, B-frags = one
//         16B load per frag from ktvT (L2-hot). No LDS anywhere.

#define BH_TOT 24
#define NROWS 4096
#define DD 64

typedef __attribute__((ext_vector_type(8))) short bf16x8;   // 8 x bf16 (4 VGPR)
typedef __attribute__((ext_vector_type(4))) float f32x4;    // MFMA C/D frag

__device__ __forceinline__ float elu1(float x) {
    return x > 0.0f ? x + 1.0f : __expf(x);
}
__device__ __forceinline__ short f2bf(float x) {
    __hip_bfloat16 h = __float2bfloat16(x);
    return *reinterpret_cast<short*>(&h);
}

// ---------------- Pass 1: per-wave partial KtV ----------------
// grid (24, NW/4), block 256. Wave handles rows widx*rowsPerWave .. +rpw-1.
// A-frag(i): lane l -> Kf[nb + (l>>4)*8 + jj][16i + (l&15)]  (k = n)
// B-frag(j): lane l -> Vm[nb + (l>>4)*8 + jj][16j + (l&15)]
__global__ __launch_bounds__(256) void la_pass1(
        const float* __restrict__ K, const float* __restrict__ V,
        const float* __restrict__ mask, float* __restrict__ partial,
        float scale, int chunksPerWave) {
    const int bh   = blockIdx.x;
    const int wave = threadIdx.x >> 6;
    const int lane = threadIdx.x & 63;
    const int widx = blockIdx.y * 4 + wave;
    const int rg   = (lane >> 4) * 8;
    const int cl   = lane & 15;

    const float* __restrict__ Kp = K + (size_t)bh * NROWS * DD;
    const float* __restrict__ Vp = V + (size_t)bh * NROWS * DD;
    const float* __restrict__ mp = mask + (size_t)(bh / 12) * NROWS;

    f32x4 acc[4][4];
#pragma unroll
    for (int i = 0; i < 4; ++i)
#pragma unroll
        for (int j = 0; j < 4; ++j) acc[i][j] = (f32x4)0.0f;

    const int n0 = widx * chunksPerWave * 32;

#pragma unroll 1
    for (int c = 0; c < chunksPerWave; ++c) {
        const int nb = n0 + c * 32 + rg;            // this lane's 8-row group
        const float* kb = Kp + (size_t)nb * DD + cl;
        const float* vb = Vp + (size_t)nb * DD + cl;
        float mrow[8], kr[8][4], vr[8][4];
#pragma unroll
        for (int jj = 0; jj < 8; ++jj) {
            mrow[jj] = mp[nb + jj];
#pragma unroll
            for (int i = 0; i < 4; ++i) {
                kr[jj][i] = kb[jj * DD + i * 16];   // imm-offset dword loads
                vr[jj][i] = vb[jj * DD + i * 16];
            }
        }
        bf16x8 af[4], bf[4];
#pragma unroll
        for (int i = 0; i < 4; ++i)
#pragma unroll
            for (int jj = 0; jj < 8; ++jj) {
                af[i][jj] = f2bf(elu1(kr[jj][i]) * (mrow[jj] * scale));
                bf[i][jj] = f2bf(vr[jj][i] * mrow[jj]);
            }
#pragma unroll
        for (int i = 0; i < 4; ++i)
#pragma unroll
            for (int j = 0; j < 4; ++j)
                acc[i][j] = __builtin_amdgcn_mfma_f32_16x16x32_bf16(
                                af[i], bf[j], acc[i][j], 0, 0, 0);
    }

    // C/D layout: col = lane&15, row = (lane>>4)*4 + reg  (within 16x16 tile)
    float* out = partial + ((size_t)bh * gridDim.y * 4 + widx) * (DD * DD);
#pragma unroll
    for (int i = 0; i < 4; ++i)
#pragma unroll
        for (int j = 0; j < 4; ++j)
#pragma unroll
            for (int r = 0; r < 4; ++r)
                out[(16 * i + (lane >> 4) * 4 + r) * DD + 16 * j + cl] = acc[i][j][r];
}

// ---------------- Pass 2: reduce partials -> bf16 ktvT[e][d] ----------------
// grid (24, 4), block 256; thread owns float4 (d = f4>>4, e = (f4&15)*4 ..+3)
__global__ __launch_bounds__(256) void la_pass2(
        const float* __restrict__ partial, __hip_bfloat16* __restrict__ ktvT,
        int nw) {
    const int bh = blockIdx.x;
    const int f4 = blockIdx.y * 256 + threadIdx.x;     // 0..1023
    const f32x4* base = (const f32x4*)(partial + (size_t)bh * nw * DD * DD) + f4;
    f32x4 s = (f32x4)0.0f;
#pragma unroll 8
    for (int w = 0; w < nw; ++w)
        s += base[(size_t)w * (DD * DD / 4)];
    const int d = f4 >> 4, e0 = (f4 & 15) * 4;
    __hip_bfloat16* o = ktvT + (size_t)bh * DD * DD + d;
#pragma unroll
    for (int q = 0; q < 4; ++q)
        o[(size_t)(e0 + q) * DD] = __float2bfloat16(s[q]);
}

// ---------------- Pass 3: X = Qf @ KtV ----------------
// grid (24, 32), block 256; wave handles 32 rows.
__global__ __launch_bounds__(256) void la_pass3(
        const float* __restrict__ Q, const __hip_bfloat16* __restrict__ ktvT,
        float* __restrict__ X, float scale) {
    const int bh   = blockIdx.x;
    const int wave = threadIdx.x >> 6;
    const int lane = threadIdx.x & 63;
    const int n0   = blockIdx.y * 128 + wave * 32;
    const int rg   = (lane >> 4) * 8;
    const int cl   = lane & 15;

    // B-frag(c,j): B[k=32c+rg+jj][col=16j+cl] = ktvT[16j+cl][32c+rg+jj] -> 16B
    bf16x8 bfr[2][4];
#pragma unroll
    for (int c2 = 0; c2 < 2; ++c2)
#pragma unroll
        for (int j = 0; j < 4; ++j) {
            const __hip_bfloat16* p = ktvT + (size_t)bh * DD * DD
                                      + (size_t)(16 * j + cl) * DD + 32 * c2 + rg;
            bfr[c2][j] = *reinterpret_cast<const bf16x8*>(p);
        }

    // A-frag(i,c): A[row=cl][k=rg+jj] = Qf[n0+16i+cl][32c+rg+jj] -> 2x float4
    const float* Qp = Q + (size_t)bh * NROWS * DD;
    bf16x8 afr[2][2];
#pragma unroll
    for (int i = 0; i < 2; ++i)
#pragma unroll
        for (int c2 = 0; c2 < 2; ++c2) {
            const float* qp = Qp + (size_t)(n0 + 16 * i + cl) * DD + 32 * c2 + rg;
            float4 q0 = ((const float4*)qp)[0];
            float4 q1 = ((const float4*)qp)[1];
            bf16x8 a;
            a[0] = f2bf(elu1(q0.x) * scale); a[1] = f2bf(elu1(q0.y) * scale);
            a[2] = f2bf(elu1(q0.z) * scale); a[3] = f2bf(elu1(q0.w) * scale);
            a[4] = f2bf(elu1(q1.x) * scale); a[5] = f2bf(elu1(q1.y) * scale);
            a[6] = f2bf(elu1(q1.z) * scale); a[7] = f2bf(elu1(q1.w) * scale);
            afr[i][c2] = a;
        }

    f32x4 acc[2][4];
#pragma unroll
    for (int i = 0; i < 2; ++i)
#pragma unroll
        for (int j = 0; j < 4; ++j) acc[i][j] = (f32x4)0.0f;

#pragma unroll
    for (int i = 0; i < 2; ++i)
#pragma unroll
        for (int j = 0; j < 4; ++j) {
            acc[i][j] = __builtin_amdgcn_mfma_f32_16x16x32_bf16(
                            afr[i][0], bfr[0][j], acc[i][j], 0, 0, 0);
            acc[i][j] = __builtin_amdgcn_mfma_f32_16x16x32_bf16(
                            afr[i][1], bfr[1][j], acc[i][j], 0, 0, 0);
        }

    float* Xp = X + (size_t)bh * NROWS * DD;
#pragma unroll
    for (int i = 0; i < 2; ++i)
#pragma unroll
        for (int j = 0; j < 4; ++j)
#pragma unroll
            for (int r = 0; r < 4; ++r)
                Xp[(size_t)(n0 + 16 * i + (lane >> 4) * 4 + r) * DD + 16 * j + cl]
                    = acc[i][j][r];
}

extern "C" void kernel_launch(void* const* d_in, const int* in_sizes, int n_in,
                              void* d_out, int out_size, void* d_ws, size_t ws_size,
                              hipStream_t stream) {
    const float* Q    = (const float*)d_in[0];
    const float* K    = (const float*)d_in[1];
    const float* V    = (const float*)d_in[2];
    const float* mask = (const float*)d_in[3];
    float* X = (float*)d_out;

    const float scale = 0.125f;   // 4096^-0.25 exactly

    // pick NW (waves per head) to fit workspace: partial = 24*NW*16KB + ktvT
    int nw = 64;
    while (nw > 4 &&
           (size_t)BH_TOT * nw * DD * DD * 4 + (size_t)BH_TOT * DD * DD * 2 > ws_size)
        nw >>= 1;
    const int chunksPerWave = NROWS / (nw * 32);

    float* partial = (float*)d_ws;
    __hip_bfloat16* ktvT =
        (__hip_bfloat16*)((char*)d_ws + (size_t)BH_TOT * nw * DD * DD * 4);

    la_pass1<<<dim3(BH_TOT, nw / 4), 256, 0, stream>>>(K, V, mask, partial,
                                                       scale, chunksPerWave);
    la_pass2<<<dim3(BH_TOT, 4), 256, 0, stream>>>(partial, ktvT, nw);
    la_pass3<<<dim3(BH_TOT, 32), 256, 0, stream>>>(Q, ktvT, X, scale);
}

// Round 5
// 32.882 us; speedup vs baseline: 5.2355x; 1.1250x over previous
//
#include <hip/hip_runtime.h>
#include <hip/hip_bf16.h>
#include <math.h>

// LinearAttention: X = Qf @ (Kf^T @ Vm) per (b,h); B=2 H=12 N=4096 D=64 fp32.
// Qf=(elu(Q)+1)*s ; Kf=(elu(K)+1)*m*s ; Vm=V*m ; s = N^-0.25 = 0.125 exact.
//
// MFMA formulation (bf16 in, fp32 accum), fragments gathered straight from
// global (no LDS staging). Split-K partials are reduced across the 4 waves of
// each block in LDS (stride-66 layout -> uniform 2-way banks = free), so each
// block writes ONE 64x64 fp32 partial: partial traffic 50MB -> 12.6MB total.

#define BH_TOT 24
#define NROWS 4096
#define DD 64
#define NB 16          // blocks per head in pass1

typedef __attribute__((ext_vector_type(8))) short bf16x8;   // 8 x bf16 (4 VGPR)
typedef __attribute__((ext_vector_type(4))) float f32x4;    // MFMA C/D frag

__device__ __forceinline__ float elu1(float x) {
    return x > 0.0f ? x + 1.0f : __expf(x);
}
__device__ __forceinline__ short f2bf(float x) {
    __hip_bfloat16 h = __float2bfloat16(x);
    return *reinterpret_cast<short*>(&h);
}

// ---------------- Pass 1: per-block partial KtV ----------------
// grid (24, NB), block 256. Wave handles 64 rows (2 chunks of 32).
// A-frag(i): lane l -> Kf[nb+jj][16i+(l&15)] ; B-frag(j): Vm[nb+jj][16j+(l&15)]
__global__ __launch_bounds__(256) void la_pass1(
        const float* __restrict__ K, const float* __restrict__ V,
        const float* __restrict__ mask, float* __restrict__ partial,
        float scale, int chunksPerWave) {
    const int bh   = blockIdx.x;
    const int blk  = blockIdx.y;
    const int wave = threadIdx.x >> 6;
    const int lane = threadIdx.x & 63;
    const int g    = lane >> 4;
    const int rg   = g * 8;
    const int cl   = lane & 15;

    const float* __restrict__ Kp = K + (size_t)bh * NROWS * DD;
    const float* __restrict__ Vp = V + (size_t)bh * NROWS * DD;
    const float* __restrict__ mp = mask + (size_t)(bh / 12) * NROWS;

    f32x4 acc[4][4];
#pragma unroll
    for (int i = 0; i < 4; ++i)
#pragma unroll
        for (int j = 0; j < 4; ++j) acc[i][j] = (f32x4)0.0f;

    const int n0 = (blk * 4 + wave) * chunksPerWave * 32;

#pragma unroll 1
    for (int c = 0; c < chunksPerWave; ++c) {
        const int nb = n0 + c * 32 + rg;            // this lane's 8-row group
        const float* kb = Kp + (size_t)nb * DD + cl;
        const float* vb = Vp + (size_t)nb * DD + cl;
        float mrow[8], kr[8][4], vr[8][4];
#pragma unroll
        for (int jj = 0; jj < 8; ++jj) {
            mrow[jj] = mp[nb + jj];
#pragma unroll
            for (int i = 0; i < 4; ++i) {
                kr[jj][i] = kb[jj * DD + i * 16];   // imm-offset dword loads
                vr[jj][i] = vb[jj * DD + i * 16];
            }
        }
        bf16x8 af[4], bfv[4];
#pragma unroll
        for (int i = 0; i < 4; ++i)
#pragma unroll
            for (int jj = 0; jj < 8; ++jj) {
                af[i][jj]  = f2bf(elu1(kr[jj][i]) * (mrow[jj] * scale));
                bfv[i][jj] = f2bf(vr[jj][i] * mrow[jj]);
            }
#pragma unroll
        for (int i = 0; i < 4; ++i)
#pragma unroll
            for (int j = 0; j < 4; ++j)
                acc[i][j] = __builtin_amdgcn_mfma_f32_16x16x32_bf16(
                                af[i], bfv[j], acc[i][j], 0, 0, 0);
    }

    // ---- cross-wave reduce in LDS (stride 66 => uniform 2-way banks) ----
    __shared__ float red[2][DD * 66];
#define RIDX(i, r, j) ((16 * (i) + 4 * g + (r)) * 66 + 16 * (j) + cl)
    if (wave >= 2) {
        float* buf = red[wave - 2];
#pragma unroll
        for (int i = 0; i < 4; ++i)
#pragma unroll
            for (int j = 0; j < 4; ++j)
#pragma unroll
                for (int r = 0; r < 4; ++r) buf[RIDX(i, r, j)] = acc[i][j][r];
    }
    __syncthreads();
    if (wave < 2) {
        const float* buf = red[wave];
#pragma unroll
        for (int i = 0; i < 4; ++i)
#pragma unroll
            for (int j = 0; j < 4; ++j)
#pragma unroll
                for (int r = 0; r < 4; ++r) acc[i][j][r] += buf[RIDX(i, r, j)];
    }
    __syncthreads();
    if (wave == 1) {
        float* buf = red[0];
#pragma unroll
        for (int i = 0; i < 4; ++i)
#pragma unroll
            for (int j = 0; j < 4; ++j)
#pragma unroll
                for (int r = 0; r < 4; ++r) buf[RIDX(i, r, j)] = acc[i][j][r];
    }
    __syncthreads();
    if (wave == 0) {
        const float* buf = red[0];
        float* out = partial + ((size_t)bh * NB + blk) * (DD * DD);
#pragma unroll
        for (int i = 0; i < 4; ++i)
#pragma unroll
            for (int j = 0; j < 4; ++j)
#pragma unroll
                for (int r = 0; r < 4; ++r)
                    out[(16 * i + 4 * g + r) * DD + 16 * j + cl]
                        = acc[i][j][r] + buf[RIDX(i, r, j)];
    }
#undef RIDX
}

// ---------------- Pass 2: reduce partials -> bf16 ktvT[e][d] ----------------
// grid (24, 4), block 256; thread owns float4 (d = f4>>4, e = (f4&15)*4 ..+3)
__global__ __launch_bounds__(256) void la_pass2(
        const float* __restrict__ partial, __hip_bfloat16* __restrict__ ktvT,
        int nw) {
    const int bh = blockIdx.x;
    const int f4 = blockIdx.y * 256 + threadIdx.x;     // 0..1023
    const f32x4* base = (const f32x4*)(partial + (size_t)bh * nw * DD * DD) + f4;
    f32x4 s = (f32x4)0.0f;
#pragma unroll 8
    for (int w = 0; w < nw; ++w)
        s += base[(size_t)w * (DD * DD / 4)];
    const int d = f4 >> 4, e0 = (f4 & 15) * 4;
    __hip_bfloat16* o = ktvT + (size_t)bh * DD * DD + d;
#pragma unroll
    for (int q = 0; q < 4; ++q)
        o[(size_t)(e0 + q) * DD] = __float2bfloat16(s[q]);
}

// ---------------- Pass 3: X = Qf @ KtV ----------------
// grid (24, 32), block 256; wave handles 32 rows.
__global__ __launch_bounds__(256) void la_pass3(
        const float* __restrict__ Q, const __hip_bfloat16* __restrict__ ktvT,
        float* __restrict__ X, float scale) {
    const int bh   = blockIdx.x;
    const int wave = threadIdx.x >> 6;
    const int lane = threadIdx.x & 63;
    const int n0   = blockIdx.y * 128 + wave * 32;
    const int rg   = (lane >> 4) * 8;
    const int cl   = lane & 15;

    // B-frag(c,j): B[k=32c+rg+jj][col=16j+cl] = ktvT[16j+cl][32c+rg+jj] -> 16B
    bf16x8 bfr[2][4];
#pragma unroll
    for (int c2 = 0; c2 < 2; ++c2)
#pragma unroll
        for (int j = 0; j < 4; ++j) {
            const __hip_bfloat16* p = ktvT + (size_t)bh * DD * DD
                                      + (size_t)(16 * j + cl) * DD + 32 * c2 + rg;
            bfr[c2][j] = *reinterpret_cast<const bf16x8*>(p);
        }

    // A-frag(i,c): A[row=cl][k=rg+jj] = Qf[n0+16i+cl][32c+rg+jj] -> 2x float4
    const float* Qp = Q + (size_t)bh * NROWS * DD;
    bf16x8 afr[2][2];
#pragma unroll
    for (int i = 0; i < 2; ++i)
#pragma unroll
        for (int c2 = 0; c2 < 2; ++c2) {
            const float* qp = Qp + (size_t)(n0 + 16 * i + cl) * DD + 32 * c2 + rg;
            float4 q0 = ((const float4*)qp)[0];
            float4 q1 = ((const float4*)qp)[1];
            bf16x8 a;
            a[0] = f2bf(elu1(q0.x) * scale); a[1] = f2bf(elu1(q0.y) * scale);
            a[2] = f2bf(elu1(q0.z) * scale); a[3] = f2bf(elu1(q0.w) * scale);
            a[4] = f2bf(elu1(q1.x) * scale); a[5] = f2bf(elu1(q1.y) * scale);
            a[6] = f2bf(elu1(q1.z) * scale); a[7] = f2bf(elu1(q1.w) * scale);
            afr[i][c2] = a;
        }

    f32x4 acc[2][4];
#pragma unroll
    for (int i = 0; i < 2; ++i)
#pragma unroll
        for (int j = 0; j < 4; ++j) acc[i][j] = (f32x4)0.0f;

#pragma unroll
    for (int i = 0; i < 2; ++i)
#pragma unroll
        for (int j = 0; j < 4; ++j) {
            acc[i][j] = __builtin_amdgcn_mfma_f32_16x16x32_bf16(
                            afr[i][0], bfr[0][j], acc[i][j], 0, 0, 0);
            acc[i][j] = __builtin_amdgcn_mfma_f32_16x16x32_bf16(
                            afr[i][1], bfr[1][j], acc[i][j], 0, 0, 0);
        }

    float* Xp = X + (size_t)bh * NROWS * DD;
#pragma unroll
    for (int i = 0; i < 2; ++i)
#pragma unroll
        for (int j = 0; j < 4; ++j)
#pragma unroll
            for (int r = 0; r < 4; ++r)
                Xp[(size_t)(n0 + 16 * i + (lane >> 4) * 4 + r) * DD + 16 * j + cl]
                    = acc[i][j][r];
}

extern "C" void kernel_launch(void* const* d_in, const int* in_sizes, int n_in,
                              void* d_out, int out_size, void* d_ws, size_t ws_size,
                              hipStream_t stream) {
    const float* Q    = (const float*)d_in[0];
    const float* K    = (const float*)d_in[1];
    const float* V    = (const float*)d_in[2];
    const float* mask = (const float*)d_in[3];
    float* X = (float*)d_out;

    const float scale = 0.125f;   // 4096^-0.25 exactly

    const int chunksPerWave = NROWS / (NB * 4 * 32);   // = 2

    float* partial = (float*)d_ws;
    __hip_bfloat16* ktvT =
        (__hip_bfloat16*)((char*)d_ws + (size_t)BH_TOT * NB * DD * DD * 4);

    la_pass1<<<dim3(BH_TOT, NB), 256, 0, stream>>>(K, V, mask, partial,
                                                   scale, chunksPerWave);
    la_pass2<<<dim3(BH_TOT, 4), 256, 0, stream>>>(partial, ktvT, NB);
    la_pass3<<<dim3(BH_TOT, 32), 256, 0, stream>>>(Q, ktvT, X, scale);
}